// Round 7
// baseline (206.109 us; speedup 1.0000x reference)
//
#include <hip/hip_runtime.h>
#include <hip/hip_fp16.h>

#define F_EDGE 8
#define H 8

__device__ __forceinline__ unsigned short f2bf(float f) {
    unsigned u = __float_as_uint(f);
    unsigned r = u + 0x7fffu + ((u >> 16) & 1u);
    return (unsigned short)(r >> 16);
}
__device__ __forceinline__ float bflo(unsigned u) { return __uint_as_float(u << 16); }
__device__ __forceinline__ float bfhi(unsigned u) { return __uint_as_float(u & 0xffff0000u); }

// out[g] = blast (pool accumulates on top)
__global__ void init_out_kernel(float* __restrict__ out,
                                const float* __restrict__ blast, int n) {
    int g = blockIdx.x * blockDim.x + threadIdx.x;
    if (g < n) out[g] = blast[0];
}

// Pack per-edge record: {int src, int dst, 8x bf16 ea} = 24 B.
// One pass, amortized over both edge dispatches (stream 32 MB -> 19.2 MB).
__global__ __launch_bounds__(256) void pack_edges_kernel(
    const int* __restrict__ ei, const float* __restrict__ ea,
    uint2* __restrict__ rec, int E) {
    int e = blockIdx.x * blockDim.x + threadIdx.x;
    if (e >= E) return;
    uint2 hdr;
    hdr.x = (unsigned)ei[e];
    hdr.y = (unsigned)ei[E + e];
    const float4* av = (const float4*)(ea + (size_t)e * F_EDGE);
    float4 a0 = av[0], a1 = av[1];
    uint2 p0, p1;
    p0.x = (unsigned)f2bf(a0.x) | ((unsigned)f2bf(a0.y) << 16);
    p0.y = (unsigned)f2bf(a0.z) | ((unsigned)f2bf(a0.w) << 16);
    p1.x = (unsigned)f2bf(a1.x) | ((unsigned)f2bf(a1.y) << 16);
    p1.y = (unsigned)f2bf(a1.z) | ((unsigned)f2bf(a1.w) << 16);
    size_t b = (size_t)e * 3;
    rec[b] = hdr;
    rec[b + 1] = p0;
    rec[b + 2] = p1;
}

// Per-node factorized precompute:
//   Pt[n][j][k] = sum_i feat[n][i] * We[k][i*H+j]   (bf16)
//   q[n][j]     = sum_i feat[n][i] * be[i*H+j]      (f32)
//   seed[n][j]  = b[j] + sum_i feat[n][i]*root[i*H+j]  -> written f16 into agg
// F16IN: feat is __half[n][IN] (layer-2 reads the f16 aggregation buffer).
template <int IN, bool RELU, bool F16IN>
__global__ __launch_bounds__(256) void prep_kernel(
    const void* __restrict__ featv, const float* __restrict__ We,
    const float* __restrict__ be, const float* __restrict__ root,
    const float* __restrict__ b, unsigned short* __restrict__ Pt,
    float* __restrict__ q, __half* __restrict__ seedh, int n_nodes) {
    __shared__ float sW[IN * H * 12];
    int tid = threadIdx.x;
    for (int t = tid; t < IN * H * 12; t += 256) {
        int r = t / 12, m = t - r * 12;  // r = i*H + j
        float v = 0.f;
        if (m < 8) v = We[m * (IN * H) + r];
        else if (m == 8) v = be[r];
        else if (m == 9) v = root[r];
        sW[t] = v;
    }
    __syncthreads();

    int n = blockIdx.x * 32 + (tid >> 3);
    if (n >= n_nodes) return;
    int j = tid & 7;

    float f[IN];
    if (F16IN) {
        // IN == 8: one uint4 = 8 halves
        const uint4* fv = (const uint4*)((const unsigned short*)featv + (size_t)n * IN);
        uint4 v = fv[0];
        unsigned w[4] = {v.x, v.y, v.z, v.w};
#pragma unroll
        for (int p = 0; p < 4 && 2 * p + 1 < IN; ++p) {
            __half2 h2v = *(__half2*)&w[p];
            float2 ff = __half22float2(h2v);
            f[2 * p] = ff.x;
            f[2 * p + 1] = ff.y;
        }
    } else {
        const float4* fv = (const float4*)((const float*)featv + (size_t)n * IN);
#pragma unroll
        for (int i4 = 0; i4 < IN / 4; ++i4) {
            float4 v = fv[i4];
            f[i4 * 4 + 0] = v.x; f[i4 * 4 + 1] = v.y;
            f[i4 * 4 + 2] = v.z; f[i4 * 4 + 3] = v.w;
        }
    }
    if (RELU) {
#pragma unroll
        for (int i = 0; i < IN; ++i) f[i] = f[i] > 0.f ? f[i] : 0.f;
    }

    float p[8] = {0.f, 0.f, 0.f, 0.f, 0.f, 0.f, 0.f, 0.f};
    float qq = 0.f, hr = 0.f;
#pragma unroll
    for (int i = 0; i < IN; ++i) {
        const float* row = &sW[(i * 8 + j) * 12];
        float4 w0 = *(const float4*)row;
        float4 w1 = *(const float4*)(row + 4);
        float2 br = *(const float2*)(row + 8);
        float fi = f[i];
        p[0] = fmaf(fi, w0.x, p[0]); p[1] = fmaf(fi, w0.y, p[1]);
        p[2] = fmaf(fi, w0.z, p[2]); p[3] = fmaf(fi, w0.w, p[3]);
        p[4] = fmaf(fi, w1.x, p[4]); p[5] = fmaf(fi, w1.y, p[5]);
        p[6] = fmaf(fi, w1.z, p[6]); p[7] = fmaf(fi, w1.w, p[7]);
        qq = fmaf(fi, br.x, qq);
        hr = fmaf(fi, br.y, hr);
    }
    uint4 pw;
    pw.x = (unsigned)f2bf(p[0]) | ((unsigned)f2bf(p[1]) << 16);
    pw.y = (unsigned)f2bf(p[2]) | ((unsigned)f2bf(p[3]) << 16);
    pw.z = (unsigned)f2bf(p[4]) | ((unsigned)f2bf(p[5]) << 16);
    pw.w = (unsigned)f2bf(p[6]) | ((unsigned)f2bf(p[7]) << 16);
    *(uint4*)(Pt + ((long long)n * H + j) * F_EDGE) = pw;
    q[(long long)n * H + j] = qq;
    seedh[(long long)n * H + j] = __float2half(hr + b[j]);
}

// Edge kernel: 4 lanes per edge; lane jj owns feature pair {2jj, 2jj+1}.
//   m_j = q[src][j] + sum_k ea[e][k] * Pt[src][j][k]
//   packed-f16 atomic add of (m_2jj, m_2jj+1) into agg[dst] (halves atomic
//   transaction count vs per-feature fp32 atomics).
__global__ __launch_bounds__(256) void edge_fact_kernel(
    const uint2* __restrict__ rec,          // [E*3] packed records
    const unsigned short* __restrict__ Pt,  // [n_nodes, H, F_EDGE] bf16
    const float* __restrict__ q,            // [n_nodes, H]
    __half* __restrict__ agg,               // [n_nodes, H] f16
    int E) {
    long long gid = (long long)blockIdx.x * blockDim.x + threadIdx.x;
    int e = (int)(gid >> 2);
    if (e >= E) return;
    int jj = (int)(gid & 3);

    size_t rb = (size_t)e * 3;
    uint2 hdr = rec[rb];
    uint2 A = rec[rb + 1];
    uint2 B = rec[rb + 2];
    int src = (int)hdr.x;
    int dst = (int)hdr.y;

    float a0 = bflo(A.x), a1 = bfhi(A.x), a2 = bflo(A.y), a3 = bfhi(A.y);
    float a4 = bflo(B.x), a5 = bfhi(B.x), a6 = bflo(B.y), a7 = bfhi(B.y);

    // rows j=2jj and j=2jj+1 are 32 contiguous bytes at node-row offset jj*32
    const uint4* pp = (const uint4*)(Pt + (size_t)src * 64 + jj * 16);
    uint4 lo = pp[0];  // P[2jj][0..7]
    uint4 hi = pp[1];  // P[2jj+1][0..7]

    float2 q2 = *(const float2*)(q + (size_t)src * H + jj * 2);

    float m0 = q2.x;
    m0 = fmaf(a0, bflo(lo.x), m0); m0 = fmaf(a1, bfhi(lo.x), m0);
    m0 = fmaf(a2, bflo(lo.y), m0); m0 = fmaf(a3, bfhi(lo.y), m0);
    m0 = fmaf(a4, bflo(lo.z), m0); m0 = fmaf(a5, bfhi(lo.z), m0);
    m0 = fmaf(a6, bflo(lo.w), m0); m0 = fmaf(a7, bfhi(lo.w), m0);

    float m1 = q2.y;
    m1 = fmaf(a0, bflo(hi.x), m1); m1 = fmaf(a1, bfhi(hi.x), m1);
    m1 = fmaf(a2, bflo(hi.y), m1); m1 = fmaf(a3, bfhi(hi.y), m1);
    m1 = fmaf(a4, bflo(hi.z), m1); m1 = fmaf(a5, bfhi(hi.z), m1);
    m1 = fmaf(a6, bflo(hi.w), m1); m1 = fmaf(a7, bfhi(hi.w), m1);

    __half2* ap = (__half2*)agg + ((size_t)dst * 4 + jj);
    unsafeAtomicAdd(ap, __floats2half2_rn(m0, m1));
}

// Pool: h2 is f16; per-block LDS bins, one global atomic per nonzero bin.
__global__ __launch_bounds__(256) void pool_kernel(
    const unsigned short* __restrict__ h2, const int* __restrict__ batch,
    const float* __restrict__ Wlast, float* __restrict__ out,
    int n_nodes, int n_graphs) {
    __shared__ float bins[512];
    bool use_bins = (n_graphs <= 512);
    if (use_bins) {
        for (int t = threadIdx.x; t < n_graphs; t += 256) bins[t] = 0.f;
        __syncthreads();
    }
    float wl[8];
#pragma unroll
    for (int j = 0; j < 8; ++j) wl[j] = Wlast[j];

    int base = blockIdx.x * 1024;
#pragma unroll
    for (int r = 0; r < 4; ++r) {
        int n = base + r * 256 + threadIdx.x;
        if (n < n_nodes) {
            uint4 v = *(const uint4*)(h2 + (size_t)n * H);
            unsigned w[4] = {v.x, v.y, v.z, v.w};
            float c = 0.f;
#pragma unroll
            for (int p = 0; p < 4; ++p) {
                float2 ff = __half22float2(*(__half2*)&w[p]);
                c = fmaf(fmaxf(ff.x, 0.f), wl[2 * p], c);
                c = fmaf(fmaxf(ff.y, 0.f), wl[2 * p + 1], c);
            }
            if (use_bins) atomicAdd(&bins[batch[n]], c);
            else unsafeAtomicAdd(&out[batch[n]], c);
        }
    }
    if (use_bins) {
        __syncthreads();
        for (int t = threadIdx.x; t < n_graphs; t += 256) {
            float v = bins[t];
            if (v != 0.f) unsafeAtomicAdd(&out[t], v);
        }
    }
}

extern "C" void kernel_launch(void* const* d_in, const int* in_sizes, int n_in,
                              void* d_out, int out_size, void* d_ws, size_t ws_size,
                              hipStream_t stream) {
    const float* x     = (const float*)d_in[0];
    const int*   ei    = (const int*)d_in[1];
    const float* ea    = (const float*)d_in[2];
    const int*   batch = (const int*)d_in[3];
    const float* We1   = (const float*)d_in[4];
    const float* be1   = (const float*)d_in[5];
    const float* root1 = (const float*)d_in[6];
    const float* b1    = (const float*)d_in[7];
    const float* We2   = (const float*)d_in[8];
    const float* be2   = (const float*)d_in[9];
    const float* root2 = (const float*)d_in[10];
    const float* b2    = (const float*)d_in[11];
    const float* Wlast = (const float*)d_in[12];
    const float* blast = (const float*)d_in[13];
    float* out = (float*)d_out;

    int n_nodes = in_sizes[0] / 16;
    int E = in_sizes[1] / 2;

    // workspace carve (16B-aligned)
    char* w = (char*)d_ws;
    auto carve = [&](size_t bytes) {
        char* p = w;
        w += (bytes + 15) & ~(size_t)15;
        return p;
    };
    unsigned short* Pt1 = (unsigned short*)carve((size_t)n_nodes * 64 * 2);
    unsigned short* Pt2 = (unsigned short*)carve((size_t)n_nodes * 64 * 2);
    float* q1 = (float*)carve((size_t)n_nodes * 8 * 4);
    float* q2 = (float*)carve((size_t)n_nodes * 8 * 4);
    __half* h1 = (__half*)carve((size_t)n_nodes * 8 * 2);
    __half* h2 = (__half*)carve((size_t)n_nodes * 8 * 2);
    uint2* rec = (uint2*)carve((size_t)E * 24);

    init_out_kernel<<<(out_size + 255) / 256, 256, 0, stream>>>(out, blast, out_size);

    pack_edges_kernel<<<(E + 255) / 256, 256, 0, stream>>>(ei, ea, rec, E);

    int nblocks = (n_nodes + 31) / 32;
    prep_kernel<16, false, false><<<nblocks, 256, 0, stream>>>(
        x, We1, be1, root1, b1, Pt1, q1, h1, n_nodes);

    long long lanes = (long long)E * 4;
    int eblks = (int)((lanes + 255) / 256);
    edge_fact_kernel<<<eblks, 256, 0, stream>>>(rec, Pt1, q1, h1, E);

    prep_kernel<8, true, true><<<nblocks, 256, 0, stream>>>(
        h1, We2, be2, root2, b2, Pt2, q2, h2, n_nodes);

    edge_fact_kernel<<<eblks, 256, 0, stream>>>(rec, Pt2, q2, h2, E);

    pool_kernel<<<(n_nodes + 1023) / 1024, 256, 0, stream>>>(
        (const unsigned short*)h2, batch, Wlast, out, n_nodes, out_size);
}